// Round 1
// baseline (15792.326 us; speedup 1.0000x reference)
//
#include <hip/hip_runtime.h>
#include <hip/hip_bf16.h>

constexpr int cV = 128, cD = 1024, cH = 1024, cB = 64, cT = 512;
constexpr int c4H = 4096;

typedef __attribute__((ext_vector_type(8))) short bf16x8;
typedef __attribute__((ext_vector_type(4))) float f32x4;

__device__ __forceinline__ short f2b(float f) {
  __hip_bfloat16 h = __float2bfloat16(f);
  return __builtin_bit_cast(short, h);
}
__device__ __forceinline__ float sigf(float x) { return 1.0f / (1.0f + __expf(-x)); }

// ---------------- f32 -> bf16 flat converter (8 elems / thread) ----------------
__global__ void cvt_bf16_kernel(const float* __restrict__ src, short* __restrict__ dst, int n8) {
  int q = blockIdx.x * blockDim.x + threadIdx.x;
  if (q >= n8) return;
  const float4* s = (const float4*)src + (size_t)q * 2;
  float4 a = s[0], b = s[1];
  union { short s8[8]; int4 v; } u;
  u.s8[0] = f2b(a.x); u.s8[1] = f2b(a.y); u.s8[2] = f2b(a.z); u.s8[3] = f2b(a.w);
  u.s8[4] = f2b(b.x); u.s8[5] = f2b(b.y); u.s8[6] = f2b(b.z); u.s8[7] = f2b(b.w);
  *(int4*)(dst + (size_t)q * 8) = u.v;
}

// ---------------- embedding gather -> xe[t][b][d] bf16 ----------------
__global__ void gather_kernel(const int* __restrict__ x, const float* __restrict__ embed,
                              short* __restrict__ xe) {
  int q = blockIdx.x * blockDim.x + threadIdx.x;  // 16B segment id, total T*B*128
  int d8 = q & 127;
  int tb = q >> 7;
  int b = tb & 63, t = tb >> 6;
  int vix = x[b * cT + t];
  const float4* s = (const float4*)(embed + (size_t)vix * cD + d8 * 8);
  float4 a = s[0], bb = s[1];
  union { short s8[8]; int4 v; } u;
  u.s8[0] = f2b(a.x); u.s8[1] = f2b(a.y); u.s8[2] = f2b(a.z); u.s8[3] = f2b(a.w);
  u.s8[4] = f2b(bb.x); u.s8[5] = f2b(bb.y); u.s8[6] = f2b(bb.z); u.s8[7] = f2b(bb.w);
  *(int4*)(xe + (size_t)q * 8) = u.v;
}

// ---------------- persistent recurrent kernel ----------------
struct RParams {
  const short* Wxb;       // [L][4096][1024] bf16
  const short* Whb;       // [L][4096][1024] bf16
  const float* bias;      // [L][4096]
  const short* xe;        // [T][64][1024] bf16
  short* h0buf;           // [2][64][1024] bf16
  short* outs;            // [T][64][1024] bf16 (h1 history)
  const short* zpage;     // [64][1024] bf16 zeros
  float* c0;              // [64][1024]
  float* c1;              // [64][1024]
  int* bar;
};

__device__ __forceinline__ void grid_sync(int* bar, int p, int nb) {
  __syncthreads();
  if (threadIdx.x == 0) {
    __threadfence();  // agent-scope release of all our global writes
    __hip_atomic_fetch_add(bar, 1, __ATOMIC_RELEASE, __HIP_MEMORY_SCOPE_AGENT);
    int target = nb * (p + 1);
    while (__hip_atomic_load(bar, __ATOMIC_ACQUIRE, __HIP_MEMORY_SCOPE_AGENT) < target)
      __builtin_amdgcn_s_sleep(1);
  }
  __syncthreads();
}

__launch_bounds__(256, 1)
__global__ void lstm_recurrent(RParams P) {
  __shared__ __align__(16) short aLDS[64 * 264];   // 256-k chunk of A, +8 bf16 pad/row
  __shared__ float gLDS[4 * 64 * 17];              // gates i,f,g,o [64][16] each, +1 pad

  const int tid = threadIdx.x;
  const int lane = tid & 63, wv = tid >> 6;        // wave 0..3 == gate i,f,g,o
  const int l15 = lane & 15, lhi = lane >> 4;      // frag row / k-group
  const int blk = blockIdx.x;
  const int layer = blk >> 6;                      // 0..63 -> L0, 64..127 -> L1
  const int h0c = (blk & 63) * 16;                 // 16-wide h slice

  const int brow = wv * cH + h0c + l15;            // W row this lane streams
  const short* WxRow = P.Wxb + (size_t)layer * c4H * cD + (size_t)brow * cD;
  const short* WhRow = P.Whb + (size_t)layer * c4H * cH + (size_t)brow * cH;
  const float* bias_l = P.bias + layer * c4H;
  float* cbuf = layer ? P.c1 : P.c0;
  const int nb = gridDim.x;

  for (int p = 0; p <= cT; ++p) {
    bool active;
    const short *Ax, *Ah;
    short* hout;
    if (layer == 0) {
      int t = p;
      active = (t < cT);
      Ax = P.xe + (size_t)t * cB * cD;
      Ah = P.h0buf + (size_t)((p + 1) & 1) * cB * cH;   // h0(p-1)
      hout = P.h0buf + (size_t)(p & 1) * cB * cH;       // h0(p)
    } else {
      int t = p - 1;
      active = (t >= 0);
      Ax = P.h0buf + (size_t)((p + 1) & 1) * cB * cH;   // h0(t)
      Ah = (t <= 0) ? P.zpage : (P.outs + (size_t)(t - 1) * cB * cH);  // h1(t-1)
      hout = P.outs + (size_t)(t < 0 ? 0 : t) * cB * cH;
    }

    if (active) {
      f32x4 acc[4] = {};
      for (int pass = 0; pass < 2; ++pass) {
        const short* A = pass ? Ah : Ax;
        const short* Wr = pass ? WhRow : WxRow;
        for (int kc = 0; kc < 1024; kc += 256) {
          __syncthreads();
          // stage A[0:64][kc:kc+256] -> LDS (coalesced, 8x16B per thread)
          #pragma unroll
          for (int j = 0; j < 8; ++j) {
            int s = tid + j * 256;
            int row = s >> 5, c16 = s & 31;
            int4 v = *(const int4*)(A + (size_t)row * 1024 + kc + c16 * 8);
            *(int4*)(aLDS + row * 264 + c16 * 8) = v;
          }
          __syncthreads();
          #pragma unroll
          for (int j = 0; j < 8; ++j) {
            bf16x8 bfrag = *(const bf16x8*)(Wr + kc + j * 32 + lhi * 8);
            #pragma unroll
            for (int m = 0; m < 4; ++m) {
              bf16x8 afrag = *(const bf16x8*)(aLDS + (m * 16 + l15) * 264 + j * 32 + lhi * 8);
              acc[m] = __builtin_amdgcn_mfma_f32_16x16x32_bf16(afrag, bfrag, acc[m], 0, 0, 0);
            }
          }
        }
      }
      // dump gate tiles to LDS: D row = m*16 + lhi*4 + v, col = l15
      #pragma unroll
      for (int m = 0; m < 4; ++m)
        #pragma unroll
        for (int v = 0; v < 4; ++v)
          gLDS[(wv * 64 + m * 16 + lhi * 4 + v) * 17 + l15] = acc[m][v];
      __syncthreads();
      // fused pointwise LSTM update for this block's 64x16 slice
      for (int q = tid; q < 1024; q += 256) {
        int b = q >> 4, col = q & 15;
        int hc = h0c + col;
        float iv = gLDS[(0 * 64 + b) * 17 + col] + bias_l[0 * cH + hc];
        float fv = gLDS[(1 * 64 + b) * 17 + col] + bias_l[1 * cH + hc];
        float gv = gLDS[(2 * 64 + b) * 17 + col] + bias_l[2 * cH + hc];
        float ov = gLDS[(3 * 64 + b) * 17 + col] + bias_l[3 * cH + hc];
        float cold = cbuf[b * cH + hc];
        float cn = sigf(fv) * cold + sigf(iv) * tanhf(gv);
        float hn = sigf(ov) * tanhf(cn);
        cbuf[b * cH + hc] = cn;
        hout[b * cH + hc] = f2b(hn);
      }
    }
    grid_sync(P.bar, p, nb);
  }
}

// ---------------- output projection: logits[b][t][v] = outs[t][b][:] @ Wout^T + bout ----------------
__launch_bounds__(256, 1)
__global__ void proj_kernel(const short* __restrict__ outs, const short* __restrict__ Woutb,
                            const float* __restrict__ bout, float* __restrict__ logits) {
  const int tid = threadIdx.x, lane = tid & 63, wv = tid >> 6;
  const int l15 = lane & 15, lhi = lane >> 4;
  const int t = blockIdx.x;
  const short* Arow = outs + ((size_t)t * 64 + wv * 16 + l15) * 1024;
  f32x4 acc[8] = {};
  for (int k = 0; k < 1024; k += 32) {
    bf16x8 af = *(const bf16x8*)(Arow + k + lhi * 8);
    #pragma unroll
    for (int nn = 0; nn < 8; ++nn) {
      bf16x8 bf = *(const bf16x8*)(Woutb + (size_t)(nn * 16 + l15) * 1024 + k + lhi * 8);
      acc[nn] = __builtin_amdgcn_mfma_f32_16x16x32_bf16(af, bf, acc[nn], 0, 0, 0);
    }
  }
  #pragma unroll
  for (int nn = 0; nn < 8; ++nn) {
    #pragma unroll
    for (int v = 0; v < 4; ++v) {
      int b = wv * 16 + lhi * 4 + v;
      int col = nn * 16 + l15;
      logits[(size_t)b * (cT * cV) + (size_t)t * cV + col] = acc[nn][v] + bout[col];
    }
  }
}

// ---------------- launch ----------------
extern "C" void kernel_launch(void* const* d_in, const int* in_sizes, int n_in,
                              void* d_out, int out_size, void* d_ws, size_t ws_size,
                              hipStream_t stream) {
  const int* x = (const int*)d_in[0];
  const float* embed = (const float*)d_in[1];
  const float* Wx = (const float*)d_in[2];
  const float* Wh = (const float*)d_in[3];
  const float* bias = (const float*)d_in[4];
  const float* Wout = (const float*)d_in[5];
  const float* bout = (const float*)d_in[6];
  float* logits = (float*)d_out;

  char* ws = (char*)d_ws;
  size_t off = 0;
  auto alloc = [&](size_t bytes) {
    char* p = ws + off;
    off += (bytes + 255) & ~(size_t)255;
    return p;
  };
  short* Wxb   = (short*)alloc((size_t)2 * c4H * cD * 2);
  short* Whb   = (short*)alloc((size_t)2 * c4H * cH * 2);
  short* Woutb = (short*)alloc((size_t)cV * cH * 2);
  short* xe    = (short*)alloc((size_t)cT * cB * cD * 2);
  short* outs  = (short*)alloc((size_t)cT * cB * cH * 2);
  char* state0 = ws + off;
  short* h0buf = (short*)alloc((size_t)2 * cB * cH * 2);
  short* zpage = (short*)alloc((size_t)cB * cH * 2);
  float* c0    = (float*)alloc((size_t)cB * cH * 4);
  float* c1    = (float*)alloc((size_t)cB * cH * 4);
  int* bar     = (int*)alloc(256);
  size_t state_bytes = (size_t)((ws + off) - state0);

  hipMemsetAsync(state0, 0, state_bytes, stream);

  int n8wx = 2 * c4H * cD / 8;
  cvt_bf16_kernel<<<(n8wx + 255) / 256, 256, 0, stream>>>(Wx, Wxb, n8wx);
  cvt_bf16_kernel<<<(n8wx + 255) / 256, 256, 0, stream>>>(Wh, Whb, n8wx);
  int n8wo = cV * cH / 8;
  cvt_bf16_kernel<<<(n8wo + 255) / 256, 256, 0, stream>>>(Wout, Woutb, n8wo);

  int nseg = cT * cB * (cD / 8);
  gather_kernel<<<nseg / 256, 256, 0, stream>>>(x, embed, xe);

  RParams P{Wxb, Whb, bias, xe, h0buf, outs, zpage, c0, c1, bar};
  void* args[] = { &P };
  hipLaunchCooperativeKernel((void*)lstm_recurrent, dim3(128), dim3(256), args, 0, stream);

  proj_kernel<<<cT, 256, 0, stream>>>(outs, Woutb, bout, logits);
}